// Round 2
// baseline (373.277 us; speedup 1.0000x reference)
//
#include <hip/hip_runtime.h>

// Problem constants (from reference)
#define B_N 4096
#define KE 64
#define D_E 128
#define R_N 16
#define L_N 2

typedef __attribute__((ext_vector_type(4))) float f4;

// ---------------------------------------------------------------------------
// Kernel 1: gather x0 = E[drug_idx], and agg[b, r*128+d] = sum_k (rel==r) w_k * E[ent_k][d]
// grid = B (4096), block = 128 (thread = d)
// ---------------------------------------------------------------------------
__global__ __launch_bounds__(128) void k_gather(
    const int* __restrict__ didx, const int* __restrict__ adj_e,
    const int* __restrict__ adj_r, const float* __restrict__ ew,
    const float* __restrict__ E, float* __restrict__ agg,
    float* __restrict__ x0) {
  const int b = blockIdx.x;
  const int d = threadIdx.x;  // 0..127
  __shared__ float sa[R_N * D_E];
#pragma unroll
  for (int r = 0; r < R_N; ++r) sa[r * D_E + d] = 0.f;
  x0[(size_t)b * D_E + d] = E[(size_t)didx[b] * D_E + d];
  const int* ae = adj_e + b * KE;
  const int* ar = adj_r + b * KE;
  const float* w = ew + b * KE;
#pragma unroll 4
  for (int k = 0; k < KE; ++k) {
    const int e = ae[k];
    const int r = ar[k];
    const float wk = w[k];
    // each thread exclusively owns column d -> no race, no syncthreads needed
    sa[r * D_E + d] += wk * E[(size_t)e * D_E + d];
  }
#pragma unroll
  for (int r = 0; r < R_N; ++r)
    agg[(size_t)b * (R_N * D_E) + r * D_E + d] = sa[r * D_E + d];
}

// ---------------------------------------------------------------------------
// Shared fp32 tile-GEMM machinery: BM=16, BN=128, BK=64, 128 threads.
// Thread (tb=tid>>4 in 0..7, te=tid&15): rows tb*2+{0,1}, cols te*8+{0..7}.
// As[16][65] (pad 65 -> a-broadcast reads conflict-free),
// Bs[64][132] (pad 132 keeps float4 alignment; 4-way conflict accepted for r0).
// ---------------------------------------------------------------------------
#define GEMM_INNER()                                              \
  _Pragma("unroll 16") for (int kk = 0; kk < 64; ++kk) {          \
    const float a0 = As[(tb * 2 + 0) * 65 + kk];                  \
    const float a1 = As[(tb * 2 + 1) * 65 + kk];                  \
    const f4 b0 = *(const f4*)&Bs[kk * 132 + te * 8];             \
    const f4 b1 = *(const f4*)&Bs[kk * 132 + te * 8 + 4];         \
    _Pragma("unroll") for (int j = 0; j < 4; ++j) {               \
      acc[0][j] += a0 * b0[j];                                    \
      acc[0][4 + j] += a0 * b1[j];                                \
      acc[1][j] += a1 * b0[j];                                    \
      acc[1][4 + j] += a1 * b1[j];                                \
    }                                                             \
  }

// stage A tile (16 rows x 64 cols) from A[(row0+r)*lda + k0 ...]
#define STAGE_A(Aptr, lda, k0)                                            \
  _Pragma("unroll") for (int s = 0; s < 2; ++s) {                         \
    const int slot = tid + 128 * s;                                       \
    const int ar_ = slot >> 4, ac4 = slot & 15;                           \
    const f4 v = *(const f4*)&(Aptr)[(size_t)(row0 + ar_) * (lda) + (k0) + ac4 * 4]; \
    As[ar_ * 65 + ac4 * 4 + 0] = v[0];                                    \
    As[ar_ * 65 + ac4 * 4 + 1] = v[1];                                    \
    As[ar_ * 65 + ac4 * 4 + 2] = v[2];                                    \
    As[ar_ * 65 + ac4 * 4 + 3] = v[3];                                    \
  }

// stage B tile natural: Bmat is [K][128] row-major, take rows k0..k0+63
#define STAGE_B_NAT(Bptr, k0)                                             \
  _Pragma("unroll") for (int s = 0; s < 16; ++s) {                        \
    const int slot = tid + 128 * s;                                       \
    const int br_ = slot >> 5, bc4 = slot & 31;                           \
    *(f4*)&Bs[br_ * 132 + bc4 * 4] =                                      \
        *(const f4*)&(Bptr)[(size_t)((k0) + br_) * 128 + bc4 * 4];        \
  }

// stage B tile transposed: Wmat is [N][K] row-major ([n][k]); Bs[kk][n]=W[n0+n][k0+kk]
#define STAGE_B_T(Wptr, ldw, n0, k0)                                      \
  _Pragma("unroll") for (int s = 0; s < 16; ++s) {                        \
    const int slot = tid + 128 * s;                                       \
    const int n_ = slot >> 4, k4 = slot & 15;                             \
    const f4 v = *(const f4*)&(Wptr)[(size_t)((n0) + n_) * (ldw) + (k0) + k4 * 4]; \
    Bs[(k4 * 4 + 0) * 132 + n_] = v[0];                                   \
    Bs[(k4 * 4 + 1) * 132 + n_] = v[1];                                   \
    Bs[(k4 * 4 + 2) * 132 + n_] = v[2];                                   \
    Bs[(k4 * 4 + 3) * 132 + n_] = v[3];                                   \
  }

// ---------------------------------------------------------------------------
// Kernel 2 (per layer): xout[b,e] = relu(xin[b,e] + sum_t agg[b,t]*Wl[t][e]
//                                        + sum_d xin[b,d]*resW[e][d] + resb[e])
// grid = B/16 = 256, block = 128
// ---------------------------------------------------------------------------
__global__ __launch_bounds__(128) void k_layer(
    const float* __restrict__ agg, const float* __restrict__ xin,
    const float* __restrict__ Wl,     // [2048][128] row-major
    const float* __restrict__ resW,   // [128][128] indexed [e][d]
    const float* __restrict__ resb,   // [128]
    float* __restrict__ xout) {
  __shared__ float As[16 * 65];
  __shared__ float Bs[64 * 132];
  const int tid = threadIdx.x;
  const int tb = tid >> 4, te = tid & 15;
  const int row0 = blockIdx.x * 16;
  float acc[2][8] = {};

  // phase 1: K = 2048 over agg x W_rel[l]
  for (int kt = 0; kt < 2048 / 64; ++kt) {
    const int k0 = kt * 64;
    STAGE_A(agg, 2048, k0)
    STAGE_B_NAT(Wl, k0)
    __syncthreads();
    GEMM_INNER()
    __syncthreads();
  }
  // phase 2: K = 128 over xin x resW^T
  for (int kt = 0; kt < 2; ++kt) {
    const int k0 = kt * 64;
    STAGE_A(xin, 128, k0)
    STAGE_B_T(resW, 128, 0, k0)
    __syncthreads();
    GEMM_INNER()
    __syncthreads();
  }
  // epilogue: + xin + resb, relu
#pragma unroll
  for (int i = 0; i < 2; ++i) {
    const int r = row0 + tb * 2 + i;
#pragma unroll
    for (int j = 0; j < 8; ++j) {
      const int c = te * 8 + j;
      float v = acc[i][j] + xin[(size_t)r * 128 + c] + resb[c];
      xout[(size_t)r * 128 + c] = v > 0.f ? v : 0.f;
    }
  }
}

// ---------------------------------------------------------------------------
// Kernel 3/5: C[m, n0+c] = sum_d A[m][d] * W[n0+c][d] + bias[n0+c]
// A is [M][128]; W is [Nfull][128]; grid (M/16, Nfull/128), block 128.
// ---------------------------------------------------------------------------
__global__ __launch_bounds__(128) void k_gemm_bT(
    const float* __restrict__ A, const float* __restrict__ W,
    const float* __restrict__ bias, float* __restrict__ C, int ldc) {
  __shared__ float As[16 * 65];
  __shared__ float Bs[64 * 132];
  const int tid = threadIdx.x;
  const int tb = tid >> 4, te = tid & 15;
  const int row0 = blockIdx.x * 16;
  const int n0 = blockIdx.y * 128;
  float acc[2][8] = {};

  for (int kt = 0; kt < 2; ++kt) {
    const int k0 = kt * 64;
    STAGE_A(A, 128, k0)
    STAGE_B_T(W, 128, n0, k0)
    __syncthreads();
    GEMM_INNER()
    __syncthreads();
  }
#pragma unroll
  for (int i = 0; i < 2; ++i) {
    const int r = row0 + tb * 2 + i;
#pragma unroll
    for (int j = 0; j < 8; ++j) {
      const int c = te * 8 + j;
      C[(size_t)r * ldc + n0 + c] = acc[i][j] + bias[n0 + c];
    }
  }
}

// ---------------------------------------------------------------------------
// Kernel 4: attention over L=2 per (b, d); heads are 32-lane groups.
// om[b,d] = 0.5 * sum_qi o[qi][b,d]   (mean folded before out-proj)
// ---------------------------------------------------------------------------
__global__ __launch_bounds__(256) void k_attn(const float* __restrict__ qkv,
                                              float* __restrict__ om) {
  const int t = blockIdx.x * 256 + threadIdx.x;  // over B*128
  const int b = t >> 7;
  const int d = t & 127;
  const float* base0 = qkv + (size_t)b * 384;            // layer 0 row
  const float* base1 = qkv + (size_t)(B_N + b) * 384;    // layer 1 row
  const float q0 = base0[d], q1 = base1[d];
  const float k0 = base0[128 + d], k1 = base1[128 + d];
  const float v0 = base0[256 + d], v1 = base1[256 + d];
  float p00 = q0 * k0, p01 = q0 * k1, p10 = q1 * k0, p11 = q1 * k1;
  // reduce over the 32-lane head group (masks < 32 stay inside the group)
#pragma unroll
  for (int m = 16; m >= 1; m >>= 1) {
    p00 += __shfl_xor(p00, m);
    p01 += __shfl_xor(p01, m);
    p10 += __shfl_xor(p10, m);
    p11 += __shfl_xor(p11, m);
  }
  const float sc = 0.17677669529663687f;  // 1/sqrt(32)
  const float s00 = p00 * sc, s01 = p01 * sc, s10 = p10 * sc, s11 = p11 * sc;
  const float m0 = fmaxf(s00, s01);
  const float e00 = __expf(s00 - m0), e01 = __expf(s01 - m0);
  const float o0 = (e00 * v0 + e01 * v1) / (e00 + e01);
  const float m1 = fmaxf(s10, s11);
  const float e10 = __expf(s10 - m1), e11 = __expf(s11 - m1);
  const float o1 = (e10 * v0 + e11 * v1) / (e10 + e11);
  om[t] = 0.5f * (o0 + o1);
}

// ---------------------------------------------------------------------------
extern "C" void kernel_launch(void* const* d_in, const int* in_sizes, int n_in,
                              void* d_out, int out_size, void* d_ws, size_t ws_size,
                              hipStream_t stream) {
  const int* didx = (const int*)d_in[0];
  const int* adj_e = (const int*)d_in[1];
  const int* adj_r = (const int*)d_in[2];
  const float* ew = (const float*)d_in[3];
  const float* E = (const float*)d_in[4];
  const float* W_rel = (const float*)d_in[5];    // [2][16][128][128]
  const float* res_W = (const float*)d_in[6];    // [2][128][128]
  const float* res_b = (const float*)d_in[7];    // [2][128]
  const float* in_w = (const float*)d_in[8];     // [384][128]
  const float* in_b = (const float*)d_in[9];     // [384]
  const float* out_w = (const float*)d_in[10];   // [128][128]
  const float* out_b = (const float*)d_in[11];   // [128]
  float* out = (float*)d_out;

  // workspace carve-up (floats); total ~52.5 MB
  float* ws = (float*)d_ws;
  float* agg = ws;                                  // B*2048
  float* x0 = agg + (size_t)B_N * 2048;             // B*128
  float* outs = x0 + (size_t)B_N * 128;             // 2*B*128 (attn_in)
  float* qkv = outs + (size_t)2 * B_N * 128;        // 2*B*384
  float* om = qkv + (size_t)2 * B_N * 384;          // B*128

  k_gather<<<B_N, 128, 0, stream>>>(didx, adj_e, adj_r, ew, E, agg, x0);

  // layer 0: xin = x0 -> outs[0]
  k_layer<<<B_N / 16, 128, 0, stream>>>(agg, x0, W_rel, res_W, res_b, outs);
  // layer 1: xin = outs[0] -> outs[1]
  k_layer<<<B_N / 16, 128, 0, stream>>>(agg, outs, W_rel + (size_t)2048 * 128,
                                        res_W + 128 * 128, res_b + 128,
                                        outs + (size_t)B_N * 128);

  // qkv projection: attn_in [8192][128] x in_w^T -> [8192][384]
  k_gemm_bT<<<dim3(2 * B_N / 16, 3), 128, 0, stream>>>(outs, in_w, in_b, qkv, 384);

  // attention + mean fold
  k_attn<<<(B_N * 128) / 256, 256, 0, stream>>>(qkv, om);

  // out projection -> d_out [4096][128]
  k_gemm_bT<<<dim3(B_N / 16, 1), 128, 0, stream>>>(om, out_w, out_b, out, 128);
}

// Round 4
// 177.123 us; speedup vs baseline: 2.1075x; 2.1075x over previous
//
#include <hip/hip_runtime.h>

#define B_N 4096
#define KE 64
#define R_N 16

typedef unsigned short u16;
typedef __attribute__((ext_vector_type(4))) float f4;
typedef __attribute__((ext_vector_type(4))) float f32x4;
typedef __attribute__((ext_vector_type(8))) short bf16x8;

__device__ __forceinline__ float b2f(u16 u) {
  union { unsigned int i; float f; } z; z.i = ((unsigned int)u) << 16; return z.f;
}
__device__ __forceinline__ u16 f2b(float f) {
  union { float f; unsigned int i; } z; z.f = f;
  unsigned int r = (z.i + 0x7FFFu + ((z.i >> 16) & 1u)) >> 16;
  return (u16)r;
}

// ---------------------------------------------------------------------------
// stage a row-major bf16 tile [ROWS][8<<LOG2SLOTS k-cols] into LDS via
// global_load_lds(16B), with row-XOR slot swizzle applied on the GLOBAL source
// (LDS dest stays lane-linear; the matching XOR is applied on ds_read).
// 256 threads assumed.
// ---------------------------------------------------------------------------
template<int LOG2SLOTS, int NISS>
__device__ __forceinline__ void stage_tile(const u16* gbase, size_t gstride,
                                           u16* lds, int t) {
#pragma unroll
  for (int s = 0; s < NISS; ++s) {
    const int lin = s * 256 + t;
    const int r = lin >> LOG2SLOTS;
    const int p = lin & ((1 << LOG2SLOTS) - 1);
    const int lsl = p ^ (r & 7);
    const u16* src = gbase + (size_t)r * gstride + (lsl << 3);
    __builtin_amdgcn_global_load_lds(
        (const __attribute__((address_space(1))) void*)src,
        (__attribute__((address_space(3))) void*)(lds + (size_t)lin * 8), 16, 0, 0);
  }
}

// ---------------------------------------------------------------------------
// prep 1: WcatT[(l*128+e)][(r*128+d)] = bf16(W_rel[l][r][d][e])  (transpose d<->e)
// grid 32 = (l,r), block 256
// ---------------------------------------------------------------------------
__global__ __launch_bounds__(256) void k_prep_wcat(const float* __restrict__ W_rel,
                                                   u16* __restrict__ WcatT) {
  __shared__ __align__(16) u16 T[128][130];  // pad 130
  const int lr = blockIdx.x;   // l*16 + r
  const int t = threadIdx.x;
  const float* src = W_rel + (size_t)lr * 128 * 128;  // [d][e]
#pragma unroll
  for (int s = 0; s < 16; ++s) {
    const int idx4 = s * 256 + t;       // f4 index over 128x128
    const int d = idx4 >> 5, e4 = idx4 & 31;
    const f4 v = *(const f4*)(src + (size_t)d * 128 + e4 * 4);
#pragma unroll
    for (int j = 0; j < 4; ++j) T[d][e4 * 4 + j] = f2b(v[j]);
  }
  __syncthreads();
  const int l = lr >> 4, r = lr & 15;
  const int e = t >> 1, d0 = (t & 1) * 64;
  u16* dst = WcatT + (size_t)(l * 128 + e) * 2048 + r * 128 + d0;
#pragma unroll
  for (int j8 = 0; j8 < 8; ++j8) {
    bf16x8 w;
#pragma unroll
    for (int i = 0; i < 8; ++i) w[i] = (short)T[d0 + j8 * 8 + i][e];
    *(bf16x8*)(dst + j8 * 8) = w;
  }
}

// ---------------------------------------------------------------------------
// prep 2: straight fp32->bf16 casts (layouts already [N][K])
// resWT (32768) | in_wT (49152) | out_wT (16384); grid 384, block 256
// ---------------------------------------------------------------------------
__global__ __launch_bounds__(256) void k_prep_cast(const float* __restrict__ res_W,
                                                   const float* __restrict__ in_w,
                                                   const float* __restrict__ out_w,
                                                   u16* __restrict__ resWT,
                                                   u16* __restrict__ in_wT,
                                                   u16* __restrict__ out_wT) {
  const int i = blockIdx.x * 256 + threadIdx.x;
  if (i < 32768) resWT[i] = f2b(res_W[i]);
  else if (i < 81920) in_wT[i - 32768] = f2b(in_w[i - 32768]);
  else out_wT[i - 81920] = f2b(out_w[i - 81920]);
}

// ---------------------------------------------------------------------------
// gather: agg[b][r*128+d] = sum_k (rel==r) w_k*E[ent_k][d] (bf16 out), x0 = E[didx] bf16
// grid 4096, block 128 (4 edge-groups x 32 lanes, f4 loads)
// ---------------------------------------------------------------------------
__global__ __launch_bounds__(128) void k_gather(
    const int* __restrict__ didx, const int* __restrict__ adj_e,
    const int* __restrict__ adj_r, const float* __restrict__ ew,
    const float* __restrict__ E, u16* __restrict__ agg, u16* __restrict__ x0) {
  __shared__ __align__(16) float sa[4][R_N][128];  // 32 KB
  const int b = blockIdx.x;
  const int t = threadIdx.x;
  const int g = t >> 5, ln = t & 31;
  float* flat = &sa[0][0][0];
#pragma unroll
  for (int i = 0; i < 64; ++i) flat[t + 128 * i] = 0.f;
  __syncthreads();
  const int base = b * KE;
#pragma unroll 2
  for (int kg = 0; kg < 16; ++kg) {
    const int k = (kg << 2) | g;
    const int e = adj_e[base + k];
    const int r = adj_r[base + k];
    const float wk = ew[base + k];
    const f4 v = *(const f4*)(E + (size_t)e * 128 + (ln << 2));
    float* dst = &sa[g][r][ln << 2];
    dst[0] += wk * v[0]; dst[1] += wk * v[1];
    dst[2] += wk * v[2]; dst[3] += wk * v[3];
  }
  __syncthreads();
  // reduce 4 groups, pack bf16: thread t owns elements [t*16, t*16+16)
  const int o0 = t * 16;
  const int r = o0 >> 7, d0 = o0 & 127;
#pragma unroll
  for (int j2 = 0; j2 < 2; ++j2) {
    bf16x8 w;
#pragma unroll
    for (int i = 0; i < 8; ++i) {
      const int d = d0 + j2 * 8 + i;
      w[i] = (short)f2b(sa[0][r][d] + sa[1][r][d] + sa[2][r][d] + sa[3][r][d]);
    }
    *(bf16x8*)(agg + (size_t)b * 2048 + o0 + j2 * 8) = w;
  }
  x0[(size_t)b * 128 + t] = f2b(E[(size_t)didx[b] * 128 + t]);
}

// ---------------------------------------------------------------------------
// msgs GEMM: Cp[sp][4096][256] = A[4096][2048]bf16 x WcatT^T  (split-K=4)
// grid (32, 2, 4), block 256 (4 waves, 64x64 wave tiles), BK=64 double-buffered
// ---------------------------------------------------------------------------
__global__ __launch_bounds__(256) void k_msgs(const u16* __restrict__ agg,
                                              const u16* __restrict__ WcatT,
                                              float* __restrict__ Cp) {
  __shared__ __align__(16) u16 As[2][128 * 64];
  __shared__ __align__(16) u16 Bs[2][128 * 64];
  const int t = threadIdx.x;
  const int bm = blockIdx.x, bn = blockIdx.y, sp = blockIdx.z;
  const int w = t >> 6, l = t & 63;
  const int wm = w >> 1, wn = w & 1;
  const int l16 = l & 15, l4 = l >> 4;
  const u16* Abase = agg + (size_t)bm * 128 * 2048 + sp * 512;
  const u16* Bbase = WcatT + (size_t)bn * 128 * 2048 + sp * 512;
  f32x4 acc[4][4] = {};

  stage_tile<3, 4>(Abase, 2048, As[0], t);
  stage_tile<3, 4>(Bbase, 2048, Bs[0], t);
  __syncthreads();
#pragma unroll 1
  for (int c = 0; c < 8; ++c) {
    const int cur = c & 1;
    if (c < 7) {  // issue next-chunk loads BEFORE compute (2-phase template)
      stage_tile<3, 4>(Abase + (c + 1) * 64, 2048, As[cur ^ 1], t);
      stage_tile<3, 4>(Bbase + (c + 1) * 64, 2048, Bs[cur ^ 1], t);
    }
#pragma unroll
    for (int ks = 0; ks < 2; ++ks) {
      bf16x8 a[4], b[4];
#pragma unroll
      for (int mi = 0; mi < 4; ++mi) {
        const int r = wm * 64 + mi * 16 + l16;
        const int phys = ((ks << 2) + l4) ^ (r & 7);
        a[mi] = *(const bf16x8*)&As[cur][r * 64 + phys * 8];
      }
#pragma unroll
      for (int ni = 0; ni < 4; ++ni) {
        const int r = wn * 64 + ni * 16 + l16;
        const int phys = ((ks << 2) + l4) ^ (r & 7);
        b[ni] = *(const bf16x8*)&Bs[cur][r * 64 + phys * 8];
      }
#pragma unroll
      for (int mi = 0; mi < 4; ++mi)
#pragma unroll
        for (int ni = 0; ni < 4; ++ni)
          acc[mi][ni] =
              __builtin_amdgcn_mfma_f32_16x16x32_bf16(a[mi], b[ni], acc[mi][ni], 0, 0, 0);
    }
    __syncthreads();  // drains global_load_lds (vmcnt(0)) + guards LDS reuse
  }
  float* cp = Cp + (size_t)sp * B_N * 256;
#pragma unroll
  for (int mi = 0; mi < 4; ++mi) {
    const int m0 = bm * 128 + wm * 64 + mi * 16 + l4 * 4;
#pragma unroll
    for (int ni = 0; ni < 4; ++ni) {
      const int n = bn * 128 + wn * 64 + ni * 16 + l16;
#pragma unroll
      for (int j = 0; j < 4; ++j) cp[(size_t)(m0 + j) * 256 + n] = acc[mi][ni][j];
    }
  }
}

// ---------------------------------------------------------------------------
// small GEMM (K=128): C = A[M][128]bf16 x BT[N][128]bf16^T + epilogue
// MODE 0: +bias -> bf16 | MODE 1: +bias -> f32 | MODE 2: +bias+x+sum(msgsP)+relu -> bf16
// grid (M/64, N/64), block 256 (4 waves, 32x32 wave tiles)
// ---------------------------------------------------------------------------
template<int MODE>
__global__ __launch_bounds__(256) void k_small(const u16* __restrict__ A,
                                               const u16* __restrict__ BT,
                                               const float* __restrict__ bias,
                                               void* __restrict__ Cout, int ldc,
                                               const float* __restrict__ msgsP,
                                               int mcol0) {
  __shared__ __align__(16) u16 As[64 * 128];
  __shared__ __align__(16) u16 Bs[64 * 128];
  const int t = threadIdx.x;
  const int row0 = blockIdx.x * 64;
  const int n0 = blockIdx.y * 64;
  const int w = t >> 6, l = t & 63;
  const int wm = w >> 1, wn = w & 1;
  const int l16 = l & 15, l4 = l >> 4;
  stage_tile<4, 4>(A + (size_t)row0 * 128, 128, As, t);
  stage_tile<4, 4>(BT + (size_t)n0 * 128, 128, Bs, t);
  __syncthreads();
  f32x4 acc[2][2] = {};
#pragma unroll
  for (int ks = 0; ks < 4; ++ks) {
    bf16x8 a[2], b[2];
#pragma unroll
    for (int mi = 0; mi < 2; ++mi) {
      const int r = wm * 32 + mi * 16 + l16;
      const int phys = ((ks << 2) + l4) ^ (r & 7);
      a[mi] = *(const bf16x8*)&As[r * 128 + phys * 8];
    }
#pragma unroll
    for (int ni = 0; ni < 2; ++ni) {
      const int r = wn * 32 + ni * 16 + l16;
      const int phys = ((ks << 2) + l4) ^ (r & 7);
      b[ni] = *(const bf16x8*)&Bs[r * 128 + phys * 8];
    }
#pragma unroll
    for (int mi = 0; mi < 2; ++mi)
#pragma unroll
      for (int ni = 0; ni < 2; ++ni)
        acc[mi][ni] =
            __builtin_amdgcn_mfma_f32_16x16x32_bf16(a[mi], b[ni], acc[mi][ni], 0, 0, 0);
  }
  const size_t BSZ = (size_t)B_N * 256;
#pragma unroll
  for (int mi = 0; mi < 2; ++mi) {
#pragma unroll
    for (int ni = 0; ni < 2; ++ni) {
      const int n = n0 + wn * 32 + ni * 16 + l16;
#pragma unroll
      for (int j = 0; j < 4; ++j) {
        const int m = row0 + wm * 32 + mi * 16 + l4 * 4 + j;
        float v = acc[mi][ni][j] + bias[n];
        if (MODE == 2) {
          const size_t mo = (size_t)m * 256 + mcol0 + n;
          v += b2f(A[(size_t)m * 128 + n]) + msgsP[mo] + msgsP[BSZ + mo] +
               msgsP[2 * BSZ + mo] + msgsP[3 * BSZ + mo];
          v = fmaxf(v, 0.f);
        }
        if (MODE == 1)
          ((float*)Cout)[(size_t)m * ldc + n] = v;
        else
          ((u16*)Cout)[(size_t)m * ldc + n] = f2b(v);
      }
    }
  }
}

// ---------------------------------------------------------------------------
// attention over L=2 (heads = 32-lane groups), mean folded: om = 0.5*(o0+o1) bf16
// ---------------------------------------------------------------------------
__global__ __launch_bounds__(256) void k_attn(const u16* __restrict__ qkv,
                                              u16* __restrict__ om) {
  const int t = blockIdx.x * 256 + threadIdx.x;
  const int b = t >> 7, d = t & 127;
  const u16* p0 = qkv + (size_t)b * 384;
  const u16* p1 = qkv + (size_t)(B_N + b) * 384;
  const float q0 = b2f(p0[d]), q1 = b2f(p1[d]);
  const float k0 = b2f(p0[128 + d]), k1 = b2f(p1[128 + d]);
  const float v0 = b2f(p0[256 + d]), v1 = b2f(p1[256 + d]);
  float p00 = q0 * k0, p01 = q0 * k1, p10 = q1 * k0, p11 = q1 * k1;
#pragma unroll
  for (int m = 16; m >= 1; m >>= 1) {
    p00 += __shfl_xor(p00, m);
    p01 += __shfl_xor(p01, m);
    p10 += __shfl_xor(p10, m);
    p11 += __shfl_xor(p11, m);
  }
  const float sc = 0.17677669529663687f;  // 1/sqrt(32)
  const float s00 = p00 * sc, s01 = p01 * sc, s10 = p10 * sc, s11 = p11 * sc;
  const float m0 = fmaxf(s00, s01);
  const float e00 = __expf(s00 - m0), e01 = __expf(s01 - m0);
  const float o0 = (e00 * v0 + e01 * v1) / (e00 + e01);
  const float m1 = fmaxf(s10, s11);
  const float e10 = __expf(s10 - m1), e11 = __expf(s11 - m1);
  const float o1 = (e10 * v0 + e11 * v1) / (e10 + e11);
  om[t] = f2b(0.5f * (o0 + o1));
}

// ---------------------------------------------------------------------------
extern "C" void kernel_launch(void* const* d_in, const int* in_sizes, int n_in,
                              void* d_out, int out_size, void* d_ws, size_t ws_size,
                              hipStream_t stream) {
  const int* didx = (const int*)d_in[0];
  const int* adj_e = (const int*)d_in[1];
  const int* adj_r = (const int*)d_in[2];
  const float* ew = (const float*)d_in[3];
  const float* E = (const float*)d_in[4];
  const float* W_rel = (const float*)d_in[5];
  const float* res_W = (const float*)d_in[6];
  const float* res_b = (const float*)d_in[7];
  const float* in_w = (const float*)d_in[8];
  const float* in_b = (const float*)d_in[9];
  const float* out_w = (const float*)d_in[10];
  const float* out_b = (const float*)d_in[11];

  char* ws = (char*)d_ws;
  u16* agg = (u16*)(ws + 0);                     // 16 MB
  u16* WcatT = (u16*)(ws + 16777216);            // 1 MB
  u16* resWT = (u16*)(ws + 17825792);            // 64 KB
  u16* in_wT = (u16*)(ws + 17891328);            // 96 KB
  u16* out_wT = (u16*)(ws + 17989632);           // 32 KB
  u16* x0 = (u16*)(ws + 18022400);               // 1 MB
  u16* xs = (u16*)(ws + 19070976);               // 2 MB  [2][4096][128]
  u16* qkv = (u16*)(ws + 21168128);              // 6 MB  [2][4096][384]
  u16* om = (u16*)(ws + 27459584);               // 1 MB
  float* Cp = (float*)(ws + 28508160);           // 16 MB [4][4096][256]

  k_prep_wcat<<<32, 256, 0, stream>>>(W_rel, WcatT);
  k_prep_cast<<<384, 256, 0, stream>>>(res_W, in_w, out_w, resWT, in_wT, out_wT);
  k_gather<<<B_N, 128, 0, stream>>>(didx, adj_e, adj_r, ew, E, agg, x0);
  k_msgs<<<dim3(32, 2, 4), 256, 0, stream>>>(agg, WcatT, Cp);

  // layer updates: x1 = relu(x0 + msgs0 + x0*resW0^T + b0); x2 likewise
  k_small<2><<<dim3(64, 2), 256, 0, stream>>>(x0, resWT, res_b, xs, 128, Cp, 0);
  k_small<2><<<dim3(64, 2), 256, 0, stream>>>(xs, resWT + 16384, res_b + 128,
                                              xs + (size_t)B_N * 128, 128, Cp, 128);
  // qkv projection over [x1; x2] (M=8192, N=384)
  k_small<0><<<dim3(128, 6), 256, 0, stream>>>(xs, in_wT, in_b, qkv, 384, nullptr, 0);
  k_attn<<<(B_N * 128) / 256, 256, 0, stream>>>(qkv, om);
  // out projection -> f32 d_out
  k_small<1><<<dim3(64, 2), 256, 0, stream>>>(om, out_wT, out_b, d_out, 128, nullptr, 0);
}